// Round 1
// 239.217 us; speedup vs baseline: 1.0229x; 1.0229x over previous
//
#include <hip/hip_runtime.h>
#include <math.h>

#define IMG_W 512
#define IMG_H 512
#define NPLANES 48      // 16 * 3
#define RROWS 32        // output rows per wave (512 = 32*16 exact)
#define NCHUNK 16
#define NSTRIP 8        // 512 / 64 cols
#define WPB 4           // waves per block (256 threads)
#define NGROUP (NCHUNK / WPB)                  // 4 chunk-groups per strip
#define NBLOCKS (NPLANES * NSTRIP * NGROUP)    // 1536 blocks, 6144 waves total
#define SSIM_C1 1e-4f
#define SSIM_C2 9e-4f

struct GW { float g[11]; };

__device__ __forceinline__ float fdiv_fast(float n, float d) {
  float r = __builtin_amdgcn_rcpf(d);
  r = r * fmaf(-d, r, 2.0f);      // 1 Newton step on reciprocal
  float q = n * r;
  q = fmaf(fmaf(-d, q, n), r, q); // residual correction
  return q;
}

// 4 waves per block; each wave independently computes a 64-col x 32-row output
// tile (4 vertically adjacent chunks per block -> row-halo L1/L2 reuse).
// No __syncthreads in the hot loop: each wave owns a private double-buffered
// LDS row slice; in-wave LDS write->read ordering is enforced by compiler
// lgkmcnt waits. Single-wave workgroups (previous round) capped residency at
// ~7 waves/CU (per-CU workgroup dispatch limit -> Occupancy 21%, VALUBusy 54%);
// 4-wave workgroups lift residency to the VGPR limit (~20 waves/CU).
// __launch_bounds__(256, 2): floor of 2 waves/EU -> VGPR cap 256; the ~88-reg
// ring stays in arch VGPRs (cap of 100 previously forced AGPR shuttles).
// 7 ring streams: A, B, F, (A^2+F^2), (B^2+F^2), AF, BF -- variance sums
// merged at ring-write time (conv linearity; verified exact previously).
__global__ __launch_bounds__(256, 2) void ssim_main(
    const float* __restrict__ A, const float* __restrict__ B,
    const float* __restrict__ F, double* __restrict__ partials, GW gw)
{
  __shared__ float sA[WPB][2][80], sB[WPB][2][80], sF[WPB][2][80];
  __shared__ double sred[WPB];
  const int b = blockIdx.x;
  const int plane = b / (NSTRIP * NGROUP);
  const int rem   = b % (NSTRIP * NGROUP);
  const int strip = rem / NGROUP;
  const int grp   = rem % NGROUP;
  const int wid = threadIdx.x >> 6;      // wave id 0..3
  const int t   = threadIdx.x & 63;      // lane id
  const int chunk = grp * WPB + wid;     // 0..15
  const int x0 = strip * 64;
  const int y0 = chunk * RROWS;
  const size_t pbase = (size_t)plane * (IMG_W * IMG_H);
  const float* Ap = A + pbase;
  const float* Bp = B + pbase;
  const float* Fp = F + pbase;

  // this wave's private LDS slices
  float (&mA)[2][80] = sA[wid];
  float (&mB)[2][80] = sB[wid];
  float (&mF)[2][80] = sF[wid];

  const int c  = x0 - 5 + t;                 // primary load column
  const bool cok = (c >= 0) && (c < IMG_W);
  const int c2 = c + 64;                     // halo column (lanes 0..9)
  const bool c2ok = (t < 10) && (c2 < IMG_W);

  // ring[stream][slot]: horizontally-convolved rows, slot = input-row mod 11
  float ring[7][11];
  #pragma unroll
  for (int s = 0; s < 7; ++s)
    #pragma unroll
    for (int k = 0; k < 11; ++k) ring[s][k] = 0.f;

  float acc = 0.f;

  // prefetch registers for the software pipeline
  float rA, rB, rF, xA, xB, xF;
  auto load_row = [&](int ii) {
    const int yin = y0 - 5 + ii;
    const bool rok = (yin >= 0) && (yin < IMG_H);
    const size_t roff = (size_t)yin * IMG_W;
    rA = (rok && cok) ? Ap[roff + c] : 0.f;
    rB = (rok && cok) ? Bp[roff + c] : 0.f;
    rF = (rok && cok) ? Fp[roff + c] : 0.f;
    xA = (rok && c2ok) ? Ap[roff + c2] : 0.f;
    xB = (rok && c2ok) ? Bp[roff + c2] : 0.f;
    xF = (rok && c2ok) ? Fp[roff + c2] : 0.f;
  };

  load_row(0);   // preload row 0

  for (int jj = 0; jj < 4; ++jj) {
    #pragma unroll
    for (int ph = 0; ph < 11; ++ph) {
      const int ii = jj * 11 + ph;           // input-row counter; ii % 11 == ph
      if (ii <= RROWS + 9) {                 // 0..41
        const int buf = ii & 1;
        // --- stage prefetched row into LDS (double-buffered, no barrier) ---
        mA[buf][t] = rA; mB[buf][t] = rB; mF[buf][t] = rF;
        if (t < 10) { mA[buf][t+64] = xA; mB[buf][t+64] = xB; mF[buf][t+64] = xF; }
        // --- issue NEXT row's global loads; latency hidden under the convs ---
        if (ii < RROWS + 9) load_row(ii + 1);
        // --- horizontal 11-tap conv of the 8 product streams ---
        float hA=0,hB=0,hF=0,hA2=0,hB2=0,hF2=0,hAF=0,hBF=0;
        #pragma unroll
        for (int k = 0; k < 11; ++k) {
          const float w = gw.g[k];
          const float a = mA[buf][t+k], bb = mB[buf][t+k], f = mF[buf][t+k];
          const float wa = w*a, wb = w*bb, wf = w*f;
          hA += wa; hB += wb; hF += wf;
          hA2 = fmaf(wa, a, hA2); hB2 = fmaf(wb, bb, hB2); hF2 = fmaf(wf, f, hF2);
          hAF = fmaf(wa, f, hAF); hBF = fmaf(wb, f, hBF);
        }
        // merge variance streams at ring-write (conv linearity): 7 rings
        ring[0][ph]=hA;  ring[1][ph]=hB;  ring[2][ph]=hF;
        ring[3][ph]=hA2+hF2;  ring[4][ph]=hB2+hF2;
        ring[5][ph]=hAF; ring[6][ph]=hBF;

        // --- vertical 11-tap conv + SSIM map once 11 rows are live ---
        if (ii >= 10) {                      // yout = y0+ii-10, always in range
          float m[7];
          #pragma unroll
          for (int s = 0; s < 7; ++s) m[s] = 0.f;
          #pragma unroll
          for (int k = 0; k < 11; ++k) {
            const int sl = (ph + 1 + k) % 11;   // compile-time constant
            const float w = gw.g[k];
            #pragma unroll
            for (int s = 0; s < 7; ++s) m[s] = fmaf(w, ring[s][sl], m[s]);
          }
          const float mAv=m[0], mBv=m[1], mFv=m[2];
          const float vS1=m[3], vS2=m[4], vAF=m[5], vBF=m[6];
          const float mA2=mAv*mAv, mB2=mBv*mBv, mF2=mFv*mFv,
                      mAF=mAv*mFv, mBF=mBv*mFv;
          const float sAF = vAF - mAF, sBF = vBF - mBF;
          const float ts1 = vS1 - mA2 - mF2;   // sigmaA^2 + sigmaF^2
          const float ts2 = vS2 - mB2 - mF2;   // sigmaB^2 + sigmaF^2
          const float n1 = fmaf(2.f, mAF, SSIM_C1) * fmaf(2.f, sAF, SSIM_C2);
          const float d1 = (mA2 + mF2 + SSIM_C1) * (ts1 + SSIM_C2);
          const float n2 = fmaf(2.f, mBF, SSIM_C1) * fmaf(2.f, sBF, SSIM_C2);
          const float d2 = (mB2 + mF2 + SSIM_C1) * (ts2 + SSIM_C2);
          acc += fdiv_fast(n1, d1) + fdiv_fast(n2, d2);
        }
      }
    }
  }

  // wave (64-lane) reduction, then one cross-wave LDS reduce per block
  float wsum = acc;
  #pragma unroll
  for (int off = 32; off > 0; off >>= 1)
    wsum += __shfl_down(wsum, off, 64);
  if (t == 0) sred[wid] = (double)wsum;
  __syncthreads();
  if (threadIdx.x == 0)
    partials[b] = sred[0] + sred[1] + sred[2] + sred[3];
}

__global__ __launch_bounds__(256) void ssim_final(
    const double* __restrict__ partials, float* __restrict__ out)
{
  __shared__ double sd[256];
  const int t = threadIdx.x;
  double s = 0.0;
  for (int i = t; i < NBLOCKS; i += 256) s += partials[i];
  sd[t] = s;
  __syncthreads();
  for (int off = 128; off > 0; off >>= 1) {
    if (t < off) sd[t] += sd[t + off];
    __syncthreads();
  }
  if (t == 0)
    out[0] = (float)(0.5 * sd[0] / (double)(16.0 * 3.0 * 512.0 * 512.0));
}

extern "C" void kernel_launch(void* const* d_in, const int* in_sizes, int n_in,
                              void* d_out, int out_size, void* d_ws, size_t ws_size,
                              hipStream_t stream) {
  const float* A = (const float*)d_in[0];
  const float* B = (const float*)d_in[1];
  const float* F = (const float*)d_in[2];
  double* partials = (double*)d_ws;   // NBLOCKS doubles = 12 KB

  GW gw;
  double g[11], s = 0.0;
  for (int i = 0; i < 11; ++i) { g[i] = exp(-((double)((i-5)*(i-5))) / 4.5); s += g[i]; }
  for (int i = 0; i < 11; ++i) gw.g[i] = (float)(g[i] / s);

  hipLaunchKernelGGL(ssim_main, dim3(NBLOCKS), dim3(WPB * 64), 0, stream,
                     A, B, F, partials, gw);
  hipLaunchKernelGGL(ssim_final, dim3(1), dim3(256), 0, stream,
                     partials, (float*)d_out);
}

// Round 2
// 215.183 us; speedup vs baseline: 1.1372x; 1.1117x over previous
//
#include <hip/hip_runtime.h>
#include <math.h>

#define IMG_W 512
#define IMG_H 512
#define NPLANES 48      // 16 * 3
#define RROWS 32        // output rows per wave (512 = 32*16 exact)
#define NCHUNK 16
#define NSTRIP 8        // 512 / 64 cols
#define WPB 4           // waves per block (256 threads)
#define NGROUP (NCHUNK / WPB)                  // 4 chunk-groups per strip
#define NBLOCKS (NPLANES * NSTRIP * NGROUP)    // 1536 blocks, 6144 waves total
#define SSIM_C1 1e-4f
#define SSIM_C2 9e-4f

typedef float f32x2 __attribute__((ext_vector_type(2)));

struct GW { float g[11]; };

__device__ __forceinline__ f32x2 splat2(float v) { return (f32x2){v, v}; }
__device__ __forceinline__ f32x2 fma2(f32x2 a, f32x2 b, f32x2 c) {
  return __builtin_elementwise_fma(a, b, c);   // -> v_pk_fma_f32 on gfx950
}

__device__ __forceinline__ float fdiv_fast(float n, float d) {
  float r = __builtin_amdgcn_rcpf(d);
  r = r * fmaf(-d, r, 2.0f);      // 1 Newton step on reciprocal
  float q = n * r;
  q = fmaf(fmaf(-d, q, n), r, q); // residual correction
  return q;
}

// Row-packed pipeline: each iteration stages TWO input rows and runs the
// horizontal 11-tap conv as packed f32x2 math (v_pk_fma_f32: 2 FP32 FMA per
// lane per instr). Packing along ROWS keeps every horizontal window an
// ALIGNED float2 (row0[t+k], row1[t+k]) -> no cross-half shuffles, and each
// column's tap order is unchanged -> bit-identical to the scalar kernel.
// Vertical conv slides along the packed axis (parity issue), so it stays
// scalar over ring halves (also bit-identical). SSIM map algebra is packed
// (per-pixel ops, identical order). Static VALU per output pixel ~282->~187.
// Ring: f32x2[7][6] rotating over 6 row-pair slots (12 rows; 11-tap needs 12
// for 2 outputs). 21 pair-iterations cover the 42 input rows.
__global__ __launch_bounds__(256, 2) void ssim_main(
    const float* __restrict__ A, const float* __restrict__ B,
    const float* __restrict__ F, double* __restrict__ partials, GW gw)
{
  __shared__ float sA[WPB][2][2][80], sB[WPB][2][2][80], sF[WPB][2][2][80];
  __shared__ double sred[WPB];
  const int b = blockIdx.x;
  const int plane = b / (NSTRIP * NGROUP);
  const int rem   = b % (NSTRIP * NGROUP);
  const int strip = rem / NGROUP;
  const int grp   = rem % NGROUP;
  const int wid = threadIdx.x >> 6;      // wave id 0..3
  const int t   = threadIdx.x & 63;      // lane id
  const int chunk = grp * WPB + wid;     // 0..15
  const int x0 = strip * 64;
  const int y0 = chunk * RROWS;
  const size_t pbase = (size_t)plane * (IMG_W * IMG_H);
  const float* Ap = A + pbase;
  const float* Bp = B + pbase;
  const float* Fp = F + pbase;

  // this wave's private LDS slices: [buf][row-of-pair][col]
  float (&mA)[2][2][80] = sA[wid];
  float (&mB)[2][2][80] = sB[wid];
  float (&mF)[2][2][80] = sF[wid];

  const int c  = x0 - 5 + t;                 // primary load column
  const bool cok = (c >= 0) && (c < IMG_W);
  const int c2 = c + 64;                     // halo column (lanes 0..9)
  const bool c2ok = (t < 10) && (c2 < IMG_W);

  // ring[stream][slot]: horizontally-convolved ROW PAIRS, slot = pair mod 6
  f32x2 ring[7][6];
  #pragma unroll
  for (int s = 0; s < 7; ++s)
    #pragma unroll
    for (int k = 0; k < 6; ++k) ring[s][k] = splat2(0.f);

  float acc = 0.f;

  // prefetch registers: 2 rows x 3 arrays x (primary + halo)
  float rA0,rB0,rF0,xA0,xB0,xF0, rA1,rB1,rF1,xA1,xB1,xF1;
  auto load_pair = [&](int ii) {
    const int yin0 = y0 - 5 + 2*ii;
    const int yin1 = yin0 + 1;
    const bool r0 = (yin0 >= 0) && (yin0 < IMG_H);
    const bool r1 = (yin1 >= 0) && (yin1 < IMG_H);
    const size_t o0 = (size_t)yin0 * IMG_W;
    const size_t o1 = (size_t)yin1 * IMG_W;
    rA0 = (r0 && cok) ? Ap[o0 + c] : 0.f;
    rB0 = (r0 && cok) ? Bp[o0 + c] : 0.f;
    rF0 = (r0 && cok) ? Fp[o0 + c] : 0.f;
    rA1 = (r1 && cok) ? Ap[o1 + c] : 0.f;
    rB1 = (r1 && cok) ? Bp[o1 + c] : 0.f;
    rF1 = (r1 && cok) ? Fp[o1 + c] : 0.f;
    xA0 = (r0 && c2ok) ? Ap[o0 + c2] : 0.f;
    xB0 = (r0 && c2ok) ? Bp[o0 + c2] : 0.f;
    xF0 = (r0 && c2ok) ? Fp[o0 + c2] : 0.f;
    xA1 = (r1 && c2ok) ? Ap[o1 + c2] : 0.f;
    xB1 = (r1 && c2ok) ? Bp[o1 + c2] : 0.f;
    xF1 = (r1 && c2ok) ? Fp[o1 + c2] : 0.f;
  };

  load_pair(0);   // preload pair 0

  for (int jj = 0; jj < 4; ++jj) {
    #pragma unroll
    for (int ph = 0; ph < 6; ++ph) {
      const int ii = jj * 6 + ph;            // pair counter; ii % 6 == ph
      if (ii < 21) {                         // 21 pairs = 42 input rows
        const int buf = ii & 1;
        // --- stage prefetched row pair into LDS (double-buffered) ---
        mA[buf][0][t] = rA0; mA[buf][1][t] = rA1;
        mB[buf][0][t] = rB0; mB[buf][1][t] = rB1;
        mF[buf][0][t] = rF0; mF[buf][1][t] = rF1;
        if (t < 10) {
          mA[buf][0][t+64] = xA0; mA[buf][1][t+64] = xA1;
          mB[buf][0][t+64] = xB0; mB[buf][1][t+64] = xB1;
          mF[buf][0][t+64] = xF0; mF[buf][1][t+64] = xF1;
        }
        // --- issue NEXT pair's global loads; latency hidden under convs ---
        if (ii < 20) load_pair(ii + 1);
        // --- horizontal 11-tap conv, PACKED over the 2 rows ---
        f32x2 hA=splat2(0.f), hB=splat2(0.f), hF=splat2(0.f),
              hA2=splat2(0.f), hB2=splat2(0.f), hF2=splat2(0.f),
              hAF=splat2(0.f), hBF=splat2(0.f);
        #pragma unroll
        for (int k = 0; k < 11; ++k) {
          const float w = gw.g[k];
          const f32x2 a  = {mA[buf][0][t+k], mA[buf][1][t+k]};
          const f32x2 bb = {mB[buf][0][t+k], mB[buf][1][t+k]};
          const f32x2 f  = {mF[buf][0][t+k], mF[buf][1][t+k]};
          const f32x2 wv = splat2(w);
          const f32x2 wa = wv*a, wb = wv*bb, wf = wv*f;
          hA += wa; hB += wb; hF += wf;
          hA2 = fma2(wa, a, hA2); hB2 = fma2(wb, bb, hB2); hF2 = fma2(wf, f, hF2);
          hAF = fma2(wa, f, hAF); hBF = fma2(wb, f, hBF);
        }
        // merge variance streams at ring-write (conv linearity): 7 rings
        ring[0][ph]=hA;  ring[1][ph]=hB;  ring[2][ph]=hF;
        ring[3][ph]=hA2+hF2;  ring[4][ph]=hB2+hF2;
        ring[5][ph]=hAF; ring[6][ph]=hBF;

        // --- vertical 11-tap conv (scalar over ring halves) + packed SSIM ---
        if (ii >= 5) {                       // output pair j = ii-5 (rows 2j,2j+1)
          f32x2 M[7];
          #pragma unroll
          for (int s = 0; s < 7; ++s) M[s] = splat2(0.f);
          #pragma unroll
          for (int k = 0; k < 11; ++k) {
            const float w = gw.g[k];
            // lo output row uses element e=k, hi uses e=k+1 of the 12-row span
            const int plo = (ph + 1 + (k >> 1)) % 6;        // compile-time
            const int phi = (ph + 1 + ((k + 1) >> 1)) % 6;  // compile-time
            #pragma unroll
            for (int s = 0; s < 7; ++s) {
              const float elo = (k & 1)       ? ring[s][plo].y : ring[s][plo].x;
              const float ehi = ((k + 1) & 1) ? ring[s][phi].y : ring[s][phi].x;
              M[s].x = fmaf(w, elo, M[s].x);
              M[s].y = fmaf(w, ehi, M[s].y);
            }
          }
          const f32x2 mAv=M[0], mBv=M[1], mFv=M[2];
          const f32x2 vS1=M[3], vS2=M[4], vAF=M[5], vBF=M[6];
          const f32x2 mA2=mAv*mAv, mB2=mBv*mBv, mF2=mFv*mFv,
                      mAF=mAv*mFv, mBF=mBv*mFv;
          const f32x2 sAFv = vAF - mAF, sBFv = vBF - mBF;
          const f32x2 ts1 = vS1 - mA2 - mF2;   // sigmaA^2 + sigmaF^2
          const f32x2 ts2 = vS2 - mB2 - mF2;   // sigmaB^2 + sigmaF^2
          const f32x2 two = splat2(2.f), c1 = splat2(SSIM_C1), c2v = splat2(SSIM_C2);
          const f32x2 n1 = fma2(two, mAF, c1) * fma2(two, sAFv, c2v);
          const f32x2 d1 = (mA2 + mF2 + c1) * (ts1 + c2v);
          const f32x2 n2 = fma2(two, mBF, c1) * fma2(two, sBFv, c2v);
          const f32x2 d2 = (mB2 + mF2 + c1) * (ts2 + c2v);
          // accumulate in row-ascending order (bit-identical to scalar kernel)
          acc += fdiv_fast(n1.x, d1.x) + fdiv_fast(n2.x, d2.x);
          acc += fdiv_fast(n1.y, d1.y) + fdiv_fast(n2.y, d2.y);
        }
      }
    }
  }

  // wave (64-lane) reduction, then one cross-wave LDS reduce per block
  float wsum = acc;
  #pragma unroll
  for (int off = 32; off > 0; off >>= 1)
    wsum += __shfl_down(wsum, off, 64);
  if (t == 0) sred[wid] = (double)wsum;
  __syncthreads();
  if (threadIdx.x == 0)
    partials[b] = sred[0] + sred[1] + sred[2] + sred[3];
}

__global__ __launch_bounds__(256) void ssim_final(
    const double* __restrict__ partials, float* __restrict__ out)
{
  __shared__ double sd[256];
  const int t = threadIdx.x;
  double s = 0.0;
  for (int i = t; i < NBLOCKS; i += 256) s += partials[i];
  sd[t] = s;
  __syncthreads();
  for (int off = 128; off > 0; off >>= 1) {
    if (t < off) sd[t] += sd[t + off];
    __syncthreads();
  }
  if (t == 0)
    out[0] = (float)(0.5 * sd[0] / (double)(16.0 * 3.0 * 512.0 * 512.0));
}

extern "C" void kernel_launch(void* const* d_in, const int* in_sizes, int n_in,
                              void* d_out, int out_size, void* d_ws, size_t ws_size,
                              hipStream_t stream) {
  const float* A = (const float*)d_in[0];
  const float* B = (const float*)d_in[1];
  const float* F = (const float*)d_in[2];
  double* partials = (double*)d_ws;   // NBLOCKS doubles = 12 KB

  GW gw;
  double g[11], s = 0.0;
  for (int i = 0; i < 11; ++i) { g[i] = exp(-((double)((i-5)*(i-5))) / 4.5); s += g[i]; }
  for (int i = 0; i < 11; ++i) gw.g[i] = (float)(g[i] / s);

  hipLaunchKernelGGL(ssim_main, dim3(NBLOCKS), dim3(WPB * 64), 0, stream,
                     A, B, F, partials, gw);
  hipLaunchKernelGGL(ssim_final, dim3(1), dim3(256), 0, stream,
                     partials, (float*)d_out);
}

// Round 5
// 207.480 us; speedup vs baseline: 1.1794x; 1.0371x over previous
//
#include <hip/hip_runtime.h>
#include <math.h>

#define IMG_W 512
#define IMG_H 512
#define NPLANES 48      // 16 * 3
#define RROWS 32        // output rows per wave (512 = 32*16 exact)
#define NCHUNK 16
#define NSTRIP 8        // 512 / 64 cols
#define WPB 4           // waves per block (256 threads)
#define NGROUP (NCHUNK / WPB)                  // 4 chunk-groups per strip
#define NBLOCKS (NPLANES * NSTRIP * NGROUP)    // 1536 blocks, 6144 waves total
#define SSIM_C1 1e-4f
#define SSIM_C2 9e-4f

typedef float f32x2 __attribute__((ext_vector_type(2)));
typedef float f32x4 __attribute__((ext_vector_type(4)));

struct GW { float g[11]; };

__device__ __forceinline__ f32x2 splat2(float v) { return (f32x2){v, v}; }
__device__ __forceinline__ f32x2 fma2(f32x2 a, f32x2 b, f32x2 c) {
  return __builtin_elementwise_fma(a, b, c);   // -> v_pk_fma_f32 on gfx950
}

// Scalar Newton division (round-2 verified form). Packed fdiv remains
// quarantined: its guilt from round 3 is unproven (the failure was the LDS
// race below), but reintroduce only after the race fix is verified.
__device__ __forceinline__ float fdiv_fast(float n, float d) {
  float r = __builtin_amdgcn_rcpf(d);
  r = r * fmaf(-d, r, 2.0f);      // 1 Newton step on reciprocal
  float q = n * r;
  q = fmaf(fmaf(-d, q, n), r, q); // residual correction
  return q;
}

// ORDERING NOTE (the round-3/4 failure): the no-barrier LDS pipeline needs
// cross-lane write->read ordering. Per-thread, [t] and [t+k] (k>=1) are
// provably-distinct LDS addresses, so the compiler may legally reorder the
// vector ds_read before the ds_write — correct per-thread, wrong cross-lane.
// HW executes a wave's DS ops in issue order, so a COMPILER fence is
// sufficient: one asm memory clobber per iteration, placed between the stage
// writes and everything after. With the double buffer (reuse distance 2),
// iteration i's fence also sits between iteration i-1's reads and iteration
// i+1's writes, pinning both directions of code motion.
#define LDS_ORDER_FENCE() asm volatile("" ::: "memory")

// Row-pair pipeline, issue-slot-minimized:
//  * LDS columns interleaved: f32x4 (A0,A1,B0,B1) + f32x2 (F0,F1); horizontal
//    tap = 1 ds_read_b128 + 1 ds_read_b64 landing directly in aligned VGPR
//    pairs for VOP3P (removes 6 scalar ds_read_b32 + assembly movs per tap).
//  * Horizontal 11-tap conv fully packed over the 2 rows (aligned window ->
//    no shuffles, bit-identical).
//  * Vertical conv: even taps read (.x,.y) of the SAME ring slot -> packed
//    v_pk_fma_f32; odd taps scalar on register halves. Per-element fma order
//    unchanged -> bit-identical.
//  * SSIM map packed (shapes proven in round 2); division scalar.
// 7 ring streams: A, B, F, (A^2+F^2), (B^2+F^2), AF, BF (conv linearity).
__global__ __launch_bounds__(256, 2) void ssim_main(
    const float* __restrict__ A, const float* __restrict__ B,
    const float* __restrict__ F, double* __restrict__ partials, GW gw)
{
  __shared__ f32x4 sAB[WPB][2][80];   // (A0,A1,B0,B1) per column
  __shared__ f32x2 sFF[WPB][2][80];   // (F0,F1) per column
  __shared__ double sred[WPB];
  const int b = blockIdx.x;
  const int plane = b / (NSTRIP * NGROUP);
  const int rem   = b % (NSTRIP * NGROUP);
  const int strip = rem / NGROUP;
  const int grp   = rem % NGROUP;
  const int wid = threadIdx.x >> 6;      // wave id 0..3
  const int t   = threadIdx.x & 63;      // lane id
  const int chunk = grp * WPB + wid;     // 0..15
  const int x0 = strip * 64;
  const int y0 = chunk * RROWS;
  const size_t pbase = (size_t)plane * (IMG_W * IMG_H);
  const float* Ap = A + pbase;
  const float* Bp = B + pbase;
  const float* Fp = F + pbase;

  // this wave's private LDS slices
  f32x4 (&mAB)[2][80] = sAB[wid];
  f32x2 (&mFF)[2][80] = sFF[wid];

  const int c  = x0 - 5 + t;                 // primary load column
  const bool cok = (c >= 0) && (c < IMG_W);
  const int c2 = c + 64;                     // halo column (lanes 0..9)
  const bool c2ok = (t < 10) && (c2 < IMG_W);

  // ring[stream][slot]: horizontally-convolved ROW PAIRS, slot = pair mod 6
  f32x2 ring[7][6];
  #pragma unroll
  for (int s = 0; s < 7; ++s)
    #pragma unroll
    for (int k = 0; k < 6; ++k) ring[s][k] = splat2(0.f);

  float acc = 0.f;

  // prefetch registers: 2 rows x 3 arrays x (primary + halo)
  float rA0,rB0,rF0,xA0,xB0,xF0, rA1,rB1,rF1,xA1,xB1,xF1;
  auto load_pair = [&](int ii) {
    const int yin0 = y0 - 5 + 2*ii;
    const int yin1 = yin0 + 1;
    const bool r0 = (yin0 >= 0) && (yin0 < IMG_H);
    const bool r1 = (yin1 >= 0) && (yin1 < IMG_H);
    const size_t o0 = (size_t)yin0 * IMG_W;
    const size_t o1 = (size_t)yin1 * IMG_W;
    rA0 = (r0 && cok) ? Ap[o0 + c] : 0.f;
    rB0 = (r0 && cok) ? Bp[o0 + c] : 0.f;
    rF0 = (r0 && cok) ? Fp[o0 + c] : 0.f;
    rA1 = (r1 && cok) ? Ap[o1 + c] : 0.f;
    rB1 = (r1 && cok) ? Bp[o1 + c] : 0.f;
    rF1 = (r1 && cok) ? Fp[o1 + c] : 0.f;
    xA0 = (r0 && c2ok) ? Ap[o0 + c2] : 0.f;
    xB0 = (r0 && c2ok) ? Bp[o0 + c2] : 0.f;
    xF0 = (r0 && c2ok) ? Fp[o0 + c2] : 0.f;
    xA1 = (r1 && c2ok) ? Ap[o1 + c2] : 0.f;
    xB1 = (r1 && c2ok) ? Bp[o1 + c2] : 0.f;
    xF1 = (r1 && c2ok) ? Fp[o1 + c2] : 0.f;
  };

  load_pair(0);   // preload pair 0

  for (int jj = 0; jj < 4; ++jj) {
    #pragma unroll
    for (int ph = 0; ph < 6; ++ph) {
      const int ii = jj * 6 + ph;            // pair counter; ii % 6 == ph
      if (ii < 21) {                         // 21 pairs = 42 input rows
        const int buf = ii & 1;
        // --- stage prefetched row pair into LDS (vector, double-buffered) ---
        mAB[buf][t] = (f32x4){rA0, rA1, rB0, rB1};
        mFF[buf][t] = (f32x2){rF0, rF1};
        if (t < 10) {
          mAB[buf][t+64] = (f32x4){xA0, xA1, xB0, xB1};
          mFF[buf][t+64] = (f32x2){xF0, xF1};
        }
        // pin LDS program order: writes above, reads below (see note)
        LDS_ORDER_FENCE();
        // --- issue NEXT pair's global loads; latency hidden under convs ---
        if (ii < 20) load_pair(ii + 1);
        // --- horizontal 11-tap conv, PACKED over the 2 rows ---
        f32x2 hA=splat2(0.f), hB=splat2(0.f), hF=splat2(0.f),
              hA2=splat2(0.f), hB2=splat2(0.f), hF2=splat2(0.f),
              hAF=splat2(0.f), hBF=splat2(0.f);
        #pragma unroll
        for (int k = 0; k < 11; ++k) {
          const float w = gw.g[k];
          const f32x4 ab = mAB[buf][t+k];     // 1x ds_read_b128
          const f32x2 f  = mFF[buf][t+k];     // 1x ds_read_b64
          const f32x2 a  = {ab.x, ab.y};
          const f32x2 bb = {ab.z, ab.w};
          const f32x2 wv = splat2(w);
          const f32x2 wa = wv*a, wb = wv*bb, wf = wv*f;
          hA += wa; hB += wb; hF += wf;
          hA2 = fma2(wa, a, hA2); hB2 = fma2(wb, bb, hB2); hF2 = fma2(wf, f, hF2);
          hAF = fma2(wa, f, hAF); hBF = fma2(wb, f, hBF);
        }
        // merge variance streams at ring-write (conv linearity): 7 rings
        ring[0][ph]=hA;  ring[1][ph]=hB;  ring[2][ph]=hF;
        ring[3][ph]=hA2+hF2;  ring[4][ph]=hB2+hF2;
        ring[5][ph]=hAF; ring[6][ph]=hBF;

        // --- vertical 11-tap conv + packed SSIM map ---
        if (ii >= 5) {                       // output pair j = ii-5
          f32x2 M[7];
          #pragma unroll
          for (int s = 0; s < 7; ++s) M[s] = splat2(0.f);
          #pragma unroll
          for (int k = 0; k < 11; ++k) {
            const float w = gw.g[k];
            if ((k & 1) == 0) {
              // even tap: lo/hi rows use (.x,.y) of the SAME slot -> packed
              const int p = (ph + 1 + (k >> 1)) % 6;      // compile-time
              const f32x2 wv = splat2(w);
              #pragma unroll
              for (int s = 0; s < 7; ++s) M[s] = fma2(wv, ring[s][p], M[s]);
            } else {
              // odd tap: halves of adjacent slots; scalar on register halves
              const int plo = (ph + 1 + (k >> 1)) % 6;    // compile-time
              const int phi = (plo + 1) % 6;
              #pragma unroll
              for (int s = 0; s < 7; ++s) {
                M[s].x = fmaf(w, ring[s][plo].y, M[s].x);
                M[s].y = fmaf(w, ring[s][phi].x, M[s].y);
              }
            }
          }
          const f32x2 mAv=M[0], mBv=M[1], mFv=M[2];
          const f32x2 vS1=M[3], vS2=M[4], vAF=M[5], vBF=M[6];
          const f32x2 mA2=mAv*mAv, mB2=mBv*mBv, mF2=mFv*mFv,
                      mAF=mAv*mFv, mBF=mBv*mFv;
          const f32x2 sAFv = vAF - mAF, sBFv = vBF - mBF;
          const f32x2 ts1 = vS1 - mA2 - mF2;   // sigmaA^2 + sigmaF^2
          const f32x2 ts2 = vS2 - mB2 - mF2;   // sigmaB^2 + sigmaF^2
          const f32x2 two = splat2(2.f), c1 = splat2(SSIM_C1), c2v = splat2(SSIM_C2);
          const f32x2 n1 = fma2(two, mAF, c1) * fma2(two, sAFv, c2v);
          const f32x2 d1 = (mA2 + mF2 + c1) * (ts1 + c2v);
          const f32x2 n2 = fma2(two, mBF, c1) * fma2(two, sBFv, c2v);
          const f32x2 d2 = (mB2 + mF2 + c1) * (ts2 + c2v);
          // scalar Newton division, accumulate in row-ascending order
          acc += fdiv_fast(n1.x, d1.x) + fdiv_fast(n2.x, d2.x);
          acc += fdiv_fast(n1.y, d1.y) + fdiv_fast(n2.y, d2.y);
        }
      }
    }
  }

  // wave (64-lane) reduction, then one cross-wave LDS reduce per block
  float wsum = acc;
  #pragma unroll
  for (int off = 32; off > 0; off >>= 1)
    wsum += __shfl_down(wsum, off, 64);
  if (t == 0) sred[wid] = (double)wsum;
  __syncthreads();
  if (threadIdx.x == 0)
    partials[b] = sred[0] + sred[1] + sred[2] + sred[3];
}

__global__ __launch_bounds__(256) void ssim_final(
    const double* __restrict__ partials, float* __restrict__ out)
{
  __shared__ double sd[256];
  const int t = threadIdx.x;
  double s = 0.0;
  for (int i = t; i < NBLOCKS; i += 256) s += partials[i];
  sd[t] = s;
  __syncthreads();
  for (int off = 128; off > 0; off >>= 1) {
    if (t < off) sd[t] += sd[t + off];
    __syncthreads();
  }
  if (t == 0)
    out[0] = (float)(0.5 * sd[0] / (double)(16.0 * 3.0 * 512.0 * 512.0));
}

extern "C" void kernel_launch(void* const* d_in, const int* in_sizes, int n_in,
                              void* d_out, int out_size, void* d_ws, size_t ws_size,
                              hipStream_t stream) {
  const float* A = (const float*)d_in[0];
  const float* B = (const float*)d_in[1];
  const float* F = (const float*)d_in[2];
  double* partials = (double*)d_ws;   // NBLOCKS doubles = 12 KB

  GW gw;
  double g[11], s = 0.0;
  for (int i = 0; i < 11; ++i) { g[i] = exp(-((double)((i-5)*(i-5))) / 4.5); s += g[i]; }
  for (int i = 0; i < 11; ++i) gw.g[i] = (float)(g[i] / s);

  hipLaunchKernelGGL(ssim_main, dim3(NBLOCKS), dim3(WPB * 64), 0, stream,
                     A, B, F, partials, gw);
  hipLaunchKernelGGL(ssim_final, dim3(1), dim3(256), 0, stream,
                     partials, (float*)d_out);
}

// Round 6
// 198.678 us; speedup vs baseline: 1.2317x; 1.0443x over previous
//
#include <hip/hip_runtime.h>
#include <math.h>

#define IMG_W 512
#define IMG_H 512
#define NPLANES 48      // 16 * 3
#define RROWS 64        // output rows per wave (512 = 64*8 exact)
#define NCHUNK 8        // 512 / RROWS
#define NSTRIP 8        // 512 / 64 cols
#define WPB 4           // waves per block (256 threads)
#define NGROUP (NCHUNK / WPB)                  // 2 chunk-groups per strip
#define NBLOCKS (NPLANES * NSTRIP * NGROUP)    // 768 blocks = 3 blocks/CU exact
#define NPAIRS (RROWS / 2 + 5)                 // 37 input row-pairs per wave
#define SSIM_C1 1e-4f
#define SSIM_C2 9e-4f

typedef float f32x2 __attribute__((ext_vector_type(2)));
typedef float f32x4 __attribute__((ext_vector_type(4)));

struct GW { float g[11]; };

__device__ __forceinline__ f32x2 splat2(float v) { return (f32x2){v, v}; }
__device__ __forceinline__ f32x2 fma2(f32x2 a, f32x2 b, f32x2 c) {
  return __builtin_elementwise_fma(a, b, c);   // -> v_pk_fma_f32 on gfx950
}

// Packed Newton division: per-element op sequence identical to the scalar
// fdiv_fast -> bit-identical per element. Quarantine lifted: rounds 4/5
// proved the round-3 failure was the LDS ordering race (fence below), not
// this shape. If THIS round fails, the packed-neg pk_fma shape is guilty
// (the tile-height change is parameter-only) and gets permanently reverted.
__device__ __forceinline__ f32x2 fdiv_fast2(f32x2 n, f32x2 d) {
  f32x2 r = { __builtin_amdgcn_rcpf(d.x), __builtin_amdgcn_rcpf(d.y) };
  r = r * fma2(-d, r, splat2(2.0f));      // 1 Newton step on reciprocal
  f32x2 q = n * r;
  q = fma2(fma2(-d, q, n), r, q);         // residual correction
  return q;
}

// ORDERING NOTE (the round-3/4 failure): the no-barrier LDS pipeline needs
// cross-lane write->read ordering. Per-thread, [t] and [t+k] (k>=1) are
// provably-distinct LDS addresses, so the compiler may legally reorder the
// vector ds_read before the ds_write — correct per-thread, wrong cross-lane.
// HW executes a wave's DS ops in issue order, so a COMPILER fence suffices:
// one asm memory clobber per iteration between stage-writes and reads. With
// the double buffer (reuse distance 2), iteration i's fence also separates
// iteration i-1's reads from iteration i+1's writes. Verified round 5.
#define LDS_ORDER_FENCE() asm volatile("" ::: "memory")

// Row-pair pipeline, issue-slot-minimized (all verified round 5):
//  * LDS columns interleaved: f32x4 (A0,A1,B0,B1) + f32x2 (F0,F1); horizontal
//    tap = 1 ds_read_b128 + 1 ds_read_b64 straight into aligned VGPR pairs.
//  * Horizontal 11-tap conv fully packed over the 2 rows (aligned windows).
//  * Vertical conv: even taps packed (same-slot .x/.y), odd taps scalar on
//    register halves. Per-element fma order unchanged -> bit-identical.
//  * RROWS=64: 37 pair-iters for 32 output pairs (fill overhead 24%->14%
//    of the fill-invariant ~170 slots/pair). Ring index formulas depend only
//    on ph mod 6 — RROWS-independent.
// 7 ring streams: A, B, F, (A^2+F^2), (B^2+F^2), AF, BF (conv linearity).
__global__ __launch_bounds__(256, 2) void ssim_main(
    const float* __restrict__ A, const float* __restrict__ B,
    const float* __restrict__ F, double* __restrict__ partials, GW gw)
{
  __shared__ f32x4 sAB[WPB][2][80];   // (A0,A1,B0,B1) per column
  __shared__ f32x2 sFF[WPB][2][80];   // (F0,F1) per column
  __shared__ double sred[WPB];
  const int b = blockIdx.x;
  const int plane = b / (NSTRIP * NGROUP);
  const int rem   = b % (NSTRIP * NGROUP);
  const int strip = rem / NGROUP;
  const int grp   = rem % NGROUP;
  const int wid = threadIdx.x >> 6;      // wave id 0..3
  const int t   = threadIdx.x & 63;      // lane id
  const int chunk = grp * WPB + wid;     // 0..7
  const int x0 = strip * 64;
  const int y0 = chunk * RROWS;
  const size_t pbase = (size_t)plane * (IMG_W * IMG_H);
  const float* Ap = A + pbase;
  const float* Bp = B + pbase;
  const float* Fp = F + pbase;

  // this wave's private LDS slices
  f32x4 (&mAB)[2][80] = sAB[wid];
  f32x2 (&mFF)[2][80] = sFF[wid];

  const int c  = x0 - 5 + t;                 // primary load column
  const bool cok = (c >= 0) && (c < IMG_W);
  const int c2 = c + 64;                     // halo column (lanes 0..9)
  const bool c2ok = (t < 10) && (c2 < IMG_W);

  // ring[stream][slot]: horizontally-convolved ROW PAIRS, slot = pair mod 6
  f32x2 ring[7][6];
  #pragma unroll
  for (int s = 0; s < 7; ++s)
    #pragma unroll
    for (int k = 0; k < 6; ++k) ring[s][k] = splat2(0.f);

  float acc = 0.f;

  // prefetch registers: 2 rows x 3 arrays x (primary + halo)
  float rA0,rB0,rF0,xA0,xB0,xF0, rA1,rB1,rF1,xA1,xB1,xF1;
  auto load_pair = [&](int ii) {
    const int yin0 = y0 - 5 + 2*ii;
    const int yin1 = yin0 + 1;
    const bool r0 = (yin0 >= 0) && (yin0 < IMG_H);
    const bool r1 = (yin1 >= 0) && (yin1 < IMG_H);
    const size_t o0 = (size_t)yin0 * IMG_W;
    const size_t o1 = (size_t)yin1 * IMG_W;
    rA0 = (r0 && cok) ? Ap[o0 + c] : 0.f;
    rB0 = (r0 && cok) ? Bp[o0 + c] : 0.f;
    rF0 = (r0 && cok) ? Fp[o0 + c] : 0.f;
    rA1 = (r1 && cok) ? Ap[o1 + c] : 0.f;
    rB1 = (r1 && cok) ? Bp[o1 + c] : 0.f;
    rF1 = (r1 && cok) ? Fp[o1 + c] : 0.f;
    xA0 = (r0 && c2ok) ? Ap[o0 + c2] : 0.f;
    xB0 = (r0 && c2ok) ? Bp[o0 + c2] : 0.f;
    xF0 = (r0 && c2ok) ? Fp[o0 + c2] : 0.f;
    xA1 = (r1 && c2ok) ? Ap[o1 + c2] : 0.f;
    xB1 = (r1 && c2ok) ? Bp[o1 + c2] : 0.f;
    xF1 = (r1 && c2ok) ? Fp[o1 + c2] : 0.f;
  };

  load_pair(0);   // preload pair 0

  for (int jj = 0; jj < 7; ++jj) {
    #pragma unroll
    for (int ph = 0; ph < 6; ++ph) {
      const int ii = jj * 6 + ph;            // pair counter; ii % 6 == ph
      if (ii < NPAIRS) {                     // 37 pairs = 74 input rows
        const int buf = ii & 1;
        // --- stage prefetched row pair into LDS (vector, double-buffered) ---
        mAB[buf][t] = (f32x4){rA0, rA1, rB0, rB1};
        mFF[buf][t] = (f32x2){rF0, rF1};
        if (t < 10) {
          mAB[buf][t+64] = (f32x4){xA0, xA1, xB0, xB1};
          mFF[buf][t+64] = (f32x2){xF0, xF1};
        }
        // pin LDS program order: writes above, reads below (see note)
        LDS_ORDER_FENCE();
        // --- issue NEXT pair's global loads; latency hidden under convs ---
        if (ii < NPAIRS - 1) load_pair(ii + 1);
        // --- horizontal 11-tap conv, PACKED over the 2 rows ---
        f32x2 hA=splat2(0.f), hB=splat2(0.f), hF=splat2(0.f),
              hA2=splat2(0.f), hB2=splat2(0.f), hF2=splat2(0.f),
              hAF=splat2(0.f), hBF=splat2(0.f);
        #pragma unroll
        for (int k = 0; k < 11; ++k) {
          const float w = gw.g[k];
          const f32x4 ab = mAB[buf][t+k];     // 1x ds_read_b128
          const f32x2 f  = mFF[buf][t+k];     // 1x ds_read_b64
          const f32x2 a  = {ab.x, ab.y};
          const f32x2 bb = {ab.z, ab.w};
          const f32x2 wv = splat2(w);
          const f32x2 wa = wv*a, wb = wv*bb, wf = wv*f;
          hA += wa; hB += wb; hF += wf;
          hA2 = fma2(wa, a, hA2); hB2 = fma2(wb, bb, hB2); hF2 = fma2(wf, f, hF2);
          hAF = fma2(wa, f, hAF); hBF = fma2(wb, f, hBF);
        }
        // merge variance streams at ring-write (conv linearity): 7 rings
        ring[0][ph]=hA;  ring[1][ph]=hB;  ring[2][ph]=hF;
        ring[3][ph]=hA2+hF2;  ring[4][ph]=hB2+hF2;
        ring[5][ph]=hAF; ring[6][ph]=hBF;

        // --- vertical 11-tap conv + packed SSIM map ---
        if (ii >= 5) {                       // output pair j = ii-5
          f32x2 M[7];
          #pragma unroll
          for (int s = 0; s < 7; ++s) M[s] = splat2(0.f);
          #pragma unroll
          for (int k = 0; k < 11; ++k) {
            const float w = gw.g[k];
            if ((k & 1) == 0) {
              // even tap: lo/hi rows use (.x,.y) of the SAME slot -> packed
              const int p = (ph + 1 + (k >> 1)) % 6;      // compile-time
              const f32x2 wv = splat2(w);
              #pragma unroll
              for (int s = 0; s < 7; ++s) M[s] = fma2(wv, ring[s][p], M[s]);
            } else {
              // odd tap: halves of adjacent slots; scalar on register halves
              const int plo = (ph + 1 + (k >> 1)) % 6;    // compile-time
              const int phi = (plo + 1) % 6;
              #pragma unroll
              for (int s = 0; s < 7; ++s) {
                M[s].x = fmaf(w, ring[s][plo].y, M[s].x);
                M[s].y = fmaf(w, ring[s][phi].x, M[s].y);
              }
            }
          }
          const f32x2 mAv=M[0], mBv=M[1], mFv=M[2];
          const f32x2 vS1=M[3], vS2=M[4], vAF=M[5], vBF=M[6];
          const f32x2 mA2=mAv*mAv, mB2=mBv*mBv, mF2=mFv*mFv,
                      mAF=mAv*mFv, mBF=mBv*mFv;
          const f32x2 sAFv = vAF - mAF, sBFv = vBF - mBF;
          const f32x2 ts1 = vS1 - mA2 - mF2;   // sigmaA^2 + sigmaF^2
          const f32x2 ts2 = vS2 - mB2 - mF2;   // sigmaB^2 + sigmaF^2
          const f32x2 two = splat2(2.f), c1 = splat2(SSIM_C1), c2v = splat2(SSIM_C2);
          const f32x2 n1 = fma2(two, mAF, c1) * fma2(two, sAFv, c2v);
          const f32x2 d1 = (mA2 + mF2 + c1) * (ts1 + c2v);
          const f32x2 n2 = fma2(two, mBF, c1) * fma2(two, sBFv, c2v);
          const f32x2 d2 = (mB2 + mF2 + c1) * (ts2 + c2v);
          const f32x2 q1 = fdiv_fast2(n1, d1);
          const f32x2 q2 = fdiv_fast2(n2, d2);
          // accumulate in row-ascending order (bit-identical to scalar)
          acc += q1.x + q2.x;
          acc += q1.y + q2.y;
        }
      }
    }
  }

  // wave (64-lane) reduction, then one cross-wave LDS reduce per block
  float wsum = acc;
  #pragma unroll
  for (int off = 32; off > 0; off >>= 1)
    wsum += __shfl_down(wsum, off, 64);
  if (t == 0) sred[wid] = (double)wsum;
  __syncthreads();
  if (threadIdx.x == 0)
    partials[b] = sred[0] + sred[1] + sred[2] + sred[3];
}

__global__ __launch_bounds__(256) void ssim_final(
    const double* __restrict__ partials, float* __restrict__ out)
{
  __shared__ double sd[256];
  const int t = threadIdx.x;
  double s = 0.0;
  for (int i = t; i < NBLOCKS; i += 256) s += partials[i];
  sd[t] = s;
  __syncthreads();
  for (int off = 128; off > 0; off >>= 1) {
    if (t < off) sd[t] += sd[t + off];
    __syncthreads();
  }
  if (t == 0)
    out[0] = (float)(0.5 * sd[0] / (double)(16.0 * 3.0 * 512.0 * 512.0));
}

extern "C" void kernel_launch(void* const* d_in, const int* in_sizes, int n_in,
                              void* d_out, int out_size, void* d_ws, size_t ws_size,
                              hipStream_t stream) {
  const float* A = (const float*)d_in[0];
  const float* B = (const float*)d_in[1];
  const float* F = (const float*)d_in[2];
  double* partials = (double*)d_ws;   // NBLOCKS doubles = 6 KB

  GW gw;
  double g[11], s = 0.0;
  for (int i = 0; i < 11; ++i) { g[i] = exp(-((double)((i-5)*(i-5))) / 4.5); s += g[i]; }
  for (int i = 0; i < 11; ++i) gw.g[i] = (float)(g[i] / s);

  hipLaunchKernelGGL(ssim_main, dim3(NBLOCKS), dim3(WPB * 64), 0, stream,
                     A, B, F, partials, gw);
  hipLaunchKernelGGL(ssim_final, dim3(1), dim3(256), 0, stream,
                     partials, (float*)d_out);
}